// Round 7
// baseline (192.008 us; speedup 1.0000x reference)
//
#include <hip/hip_runtime.h>
#include <hip/hip_bf16.h>
#include <math.h>

// Delta-rule linear attention, chunked + MFMA bf16, bf16 state buffer.
// B=8, S=4096, D=256, L=128 -> C=32 chunks/batch, 256 chunks total.
// Fat kernels split in half (j-half / t-half) for 2 blocks/CU.
// ws: A/H buffer [256][256][256] bf16 in TRANSPOSED [j][i] layout (33.5 MB),
//     then P [256] f32.

#define B_ 8
#define S_ 4096
#define D_ 256
#define L_ 128
#define C_ (S_ / L_)      // 32
#define BC_ (B_ * C_)     // 256

typedef __attribute__((ext_vector_type(8))) short s8v;   // 8 bf16 (4 VGPR)
typedef __attribute__((ext_vector_type(4))) float f4v;   // MFMA acc
typedef unsigned short u16;
typedef unsigned int u32;

__device__ __forceinline__ u32 pk2(float lo, float hi) {  // v_cvt_pk_bf16_f32
  union { __hip_bfloat162 h; u32 u; } cv;
  cv.h = __float22bfloat162_rn(make_float2(lo, hi));
  return cv.u;
}
__device__ __forceinline__ s8v pack8(const float4 a, const float4 b) {
  union { u32 u[4]; s8v v; } r;
  r.u[0] = pk2(a.x, a.y); r.u[1] = pk2(a.z, a.w);
  r.u[2] = pk2(b.x, b.y); r.u[3] = pk2(b.z, b.w);
  return r.v;
}

// 128-step prefix log2(beta) scan by wave 0 into ls[].
__device__ __forceinline__ void beta_scan128(const float* betap, float* ls,
                                             int tid) {
  if (tid < 64) {
    float x = log2f(fmaxf(betap[tid], 1e-30f));
#pragma unroll
    for (int off = 1; off < 64; off <<= 1) {
      float y = __shfl_up(x, off);
      if (tid >= off) x += y;
    }
    ls[tid] = x;
    const float tot0 = __shfl(x, 63);
    float z = log2f(fmaxf(betap[64 + tid], 1e-30f));
#pragma unroll
    for (int off = 1; off < 64; off <<= 1) {
      float y = __shfl_up(z, off);
      if (tid >= off) z += y;
    }
    ls[64 + tid] = z + tot0;
  }
}

// ---------------------------------------------------------------------------
// Kernel 1: A[bc][j][i] = sum_{s<128} w_s k_s[i] v_s[j]  (bf16, [j][i]).
// Grid BC_*2: block handles a j-HALF (128 j).  LDS 67.6 KB -> 2 blocks/CU.
// K^T staged per s-half into SB (A-frags reg-cached), then V^T(j-half, full s)
// overwrites SB.  A written via BN bounce, coalesced.
// ---------------------------------------------------------------------------
__global__ __launch_bounds__(512, 4) void ks_summary7(
    const float* __restrict__ kg, const float* __restrict__ vg,
    const float* __restrict__ beta, u16* __restrict__ A,
    float* __restrict__ P)
{
  __shared__ float ls[L_];
  __shared__ __align__(16) u16 SB[256 * 66];   // K^T [256 i][66] / V^T [2][128 j][66]
  __shared__ __align__(16) u16 BN[64 * 264];   // bounce [64 j][264 i-pad]

  const int bx = blockIdx.x;
  const int bc = bx >> 1, jh = bx & 1;         // chunk, j-half
  const int b = bc / C_, c = bc % C_;
  const int tid = threadIdx.x;
  const float* betap = beta + (size_t)b * S_ + (size_t)c * L_;
  const float* kbase = kg + ((size_t)b * S_ + (size_t)c * L_) * D_;
  const float* vbase = vg + ((size_t)b * S_ + (size_t)c * L_) * D_;

  beta_scan128(betap, ls, tid);
  __syncthreads();
  const float ltot = ls[L_ - 1];
  if (tid == 0 && jh == 0) P[bc] = exp2f(ltot);

  const int lane = tid & 63, wave = tid >> 6;
  const int quad = lane >> 4, l15 = lane & 15;
  const int i0w = wave * 32;                   // i-strip for this wave

  s8v af[2][4];                                // reg-cached K^T frags

  // ---- stage w-scaled K^T per s-half, cache A-frags ----
#pragma unroll
  for (int h = 0; h < 2; ++h) {
    {
      const int iL = tid & 15;                 // i subgroup
      const int s0 = (tid >> 4) * 2;           // s-pair 0..62 (local)
      const int sg = h * 64 + s0;
      const float* src0 = kbase + (size_t)sg * D_;
      const float* src1 = src0 + D_;
      const float w0 = exp2f(ltot - ls[sg]);
      const float w1 = exp2f(ltot - ls[sg + 1]);
#pragma unroll
      for (int p = 0; p < 4; ++p) {
        const int i0 = p * 64 + iL * 4;
        float a0[4], a1[4];
        *(float4*)a0 = *(const float4*)(src0 + i0);
        *(float4*)a1 = *(const float4*)(src1 + i0);
#pragma unroll
        for (int u = 0; u < 4; ++u)
          *(u32*)&SB[(i0 + u) * 66 + s0] = pk2(a0[u] * w0, a1[u] * w1);
      }
    }
    __syncthreads();
#pragma unroll
    for (int mt = 0; mt < 2; ++mt)
#pragma unroll
      for (int kk = 0; kk < 2; ++kk)
        af[mt][h * 2 + kk] = *(const s8v*)&SB[(i0w + mt * 16 + l15) * 66 +
                                              kk * 32 + quad * 8];
    __syncthreads();
  }

  // ---- stage V^T for this j-half, both s-halves: SB[2][128*66] ----
  {
    const int jL = tid & 15;
    const int sp = tid >> 4;                   // 0..31
#pragma unroll
    for (int h = 0; h < 2; ++h) {
      const int s0 = sp * 2;
      const int sg = h * 64 + s0;
      const float* src0 = vbase + (size_t)sg * D_ + jh * 128;
      const float* src1 = src0 + D_;
#pragma unroll
      for (int p = 0; p < 2; ++p) {
        const int j0 = p * 64 + jL * 4;        // local j 0..127
        float a0[4], a1[4];
        *(float4*)a0 = *(const float4*)(src0 + j0);
        *(float4*)a1 = *(const float4*)(src1 + j0);
#pragma unroll
        for (int u = 0; u < 4; ++u)
          *(u32*)&SB[h * (128 * 66) + (j0 + u) * 66 + s0] = pk2(a0[u], a1[u]);
      }
    }
  }
  __syncthreads();

  u16* Ab = A + (size_t)bc * D_ * D_;

  for (int ng = 0; ng < 2; ++ng) {             // local j-groups of 64
    f4v acc[2][4];
#pragma unroll
    for (int mt = 0; mt < 2; ++mt)
#pragma unroll
      for (int nt = 0; nt < 4; ++nt) acc[mt][nt] = (f4v){0.f, 0.f, 0.f, 0.f};

#pragma unroll
    for (int ks = 0; ks < 4; ++ks) {
      const int so = (ks & 1) * 32 + quad * 8;
      s8v bv[4];
#pragma unroll
      for (int nt = 0; nt < 4; ++nt)
        bv[nt] = *(const s8v*)&SB[(ks >> 1) * (128 * 66) +
                                  (ng * 64 + nt * 16 + l15) * 66 + so];
#pragma unroll
      for (int mt = 0; mt < 2; ++mt)
#pragma unroll
        for (int nt = 0; nt < 4; ++nt)
          acc[mt][nt] = __builtin_amdgcn_mfma_f32_16x16x32_bf16(
              af[mt][ks], bv[nt], acc[mt][nt], 0, 0, 0);
    }
    // C-frags -> bounce (r runs along i: in-lane packing)
#pragma unroll
    for (int mt = 0; mt < 2; ++mt)
#pragma unroll
      for (int nt = 0; nt < 4; ++nt) {
        const int jl = nt * 16 + l15;
        uint2 w;
        w.x = pk2(acc[mt][nt][0], acc[mt][nt][1]);
        w.y = pk2(acc[mt][nt][2], acc[mt][nt][3]);
        *(uint2*)&BN[jl * 264 + i0w + mt * 16 + quad * 4] = w;
      }
    __syncthreads();
    // coalesced copy-out: 64 rows x 512 B
    {
      const int jl = tid >> 3;
      const int il = (tid & 7) * 8;
      const int jgl = jh * 128 + ng * 64 + jl;   // global j
#pragma unroll
      for (int p = 0; p < 4; ++p) {
        const int iu = il + p * 64;
        *(s8v*)&Ab[(size_t)jgl * D_ + iu] = *(const s8v*)&BN[jl * 264 + iu];
      }
    }
    __syncthreads();
  }
}

// ---------------------------------------------------------------------------
// Kernel 2: register-batched chunk scan (unchanged from R6).
// ---------------------------------------------------------------------------
__global__ __launch_bounds__(256) void ks_scan7(
    u16* __restrict__ A, const float* __restrict__ P)
{
  const int g = blockIdx.x;                       // 512 blocks
  const int b = g >> 6;                           // 64 blocks / batch
  const int unit = ((g & 63) << 8) + threadIdx.x; // uint2 unit 0..16383
  u16* base = A + (size_t)b * ((size_t)C_ * D_ * D_) + (size_t)unit * 4;
  const float* Pb = P + b * C_;

  uint2 d[C_];
#pragma unroll
  for (int c = 0; c < C_; ++c)
    d[c] = *(const uint2*)(base + (size_t)c * (D_ * D_));

  float h0 = 0.f, h1 = 0.f, h2 = 0.f, h3 = 0.f;
#pragma unroll
  for (int c = 0; c < C_; ++c) {
    const float pc = Pb[c];
    const uint2 u = d[c];
    const float a0 = __uint_as_float(u.x << 16);
    const float a1 = __uint_as_float(u.x & 0xFFFF0000u);
    const float a2 = __uint_as_float(u.y << 16);
    const float a3 = __uint_as_float(u.y & 0xFFFF0000u);
    d[c].x = pk2(h0, h1);
    d[c].y = pk2(h2, h3);
    h0 = fmaf(pc, h0, a0); h1 = fmaf(pc, h1, a1);
    h2 = fmaf(pc, h2, a2); h3 = fmaf(pc, h3, a3);
  }
#pragma unroll
  for (int c = 0; c < C_; ++c)
    *(uint2*)(base + (size_t)c * (D_ * D_)) = d[c];
}

// ---------------------------------------------------------------------------
// Kernel 3: O = Tm @ V + diag(c) Q @ H.
// Grid BC_*2: block handles a t-HALF (64 t).  LDS ~68 KB -> 2 blocks/CU.
//   QBh [64 t][264] bf16; Tm [64 t][136] bf16 (s full 128);
//   V^T staged in s-quarters [256 j][34].
// Order: QBh -> Q@H (scaled by c_t) -> T=QK^T -> Tm -> TmV per s-quarter.
// ---------------------------------------------------------------------------
__global__ __launch_bounds__(512, 4) void ks_output7(
    const float* __restrict__ qg, const float* __restrict__ kg,
    const float* __restrict__ vg, const float* __restrict__ beta,
    const u16* __restrict__ Hg, float* __restrict__ outg)
{
  __shared__ float ls[L_];
  __shared__ float cv[64];
  __shared__ __align__(16) u16 QB[64 * 264];     // [t_loc][d]   (33.8 KB)
  __shared__ __align__(16) u16 Tm[64 * 136];     // [t_loc][s]   (17.4 KB)
  __shared__ __align__(16) u16 VT[256 * 34];     // [j][s-quarter] (17.4 KB)

  const int bx = blockIdx.x;
  const int bc = bx >> 1, th = bx & 1;           // chunk, t-half
  const int b = bc / C_, c = bc % C_;
  const int tid = threadIdx.x;
  const float* betap = beta + (size_t)b * S_ + (size_t)c * L_;
  const float* qbase = qg + ((size_t)b * S_ + (size_t)c * L_) * D_;
  const float* kbase = kg + ((size_t)b * S_ + (size_t)c * L_) * D_;
  const float* vbase = vg + ((size_t)b * S_ + (size_t)c * L_) * D_;
  const u16* Hb = Hg + (size_t)bc * D_ * D_;

  beta_scan128(betap, ls, tid);

  // ---- stage QBh: rows t = th*64 + t_loc ----
  {
    const int t_loc = tid >> 3;
    const int d8 = (tid & 7) * 8;
    const float* src = qbase + (size_t)(th * 64 + t_loc) * D_;
#pragma unroll
    for (int p = 0; p < 4; ++p) {
      const int d0 = d8 + p * 64;
      const s8v pk = pack8(*(const float4*)(src + d0),
                           *(const float4*)(src + d0 + 4));
      *(s8v*)&QB[t_loc * 264 + d0] = pk;
    }
  }
  __syncthreads();
  if (tid < 64) cv[tid] = exp2f(ls[th * 64 + tid]);

  const int lane = tid & 63, wave = tid >> 6;
  const int quad = lane >> 4, l15 = lane & 15;
  const int j0w = wave * 32;

  // ---- Q @ H (A-op = H[j][i] global bf16, B-op = QBh), H pipelined ----
  f4v acc[2][4];
#pragma unroll
  for (int mt = 0; mt < 2; ++mt)
#pragma unroll
    for (int nt = 0; nt < 4; ++nt) acc[mt][nt] = (f4v){0.f, 0.f, 0.f, 0.f};

  s8v hc[2];
#pragma unroll
  for (int mt = 0; mt < 2; ++mt)
    hc[mt] = *(const s8v*)(Hb + (size_t)(j0w + mt * 16 + l15) * D_ + quad * 8);

#pragma unroll
  for (int ks = 0; ks < 8; ++ks) {
    const int io = ks * 32 + quad * 8;
    s8v hn[2] = {hc[0], hc[1]};
    if (ks < 7) {
#pragma unroll
      for (int mt = 0; mt < 2; ++mt)
        hn[mt] = *(const s8v*)(Hb + (size_t)(j0w + mt * 16 + l15) * D_ +
                               io + 32);
    }
    s8v bf[4];
#pragma unroll
    for (int nt = 0; nt < 4; ++nt)
      bf[nt] = *(const s8v*)&QB[(nt * 16 + l15) * 264 + io];
#pragma unroll
    for (int mt = 0; mt < 2; ++mt)
#pragma unroll
      for (int nt = 0; nt < 4; ++nt)
        acc[mt][nt] = __builtin_amdgcn_mfma_f32_16x16x32_bf16(
            hc[mt], bf[nt], acc[mt][nt], 0, 0, 0);
    hc[0] = hn[0]; hc[1] = hn[1];
  }
  // scale by c_t (t = nt*16 + l15, constant per lane per nt)
#pragma unroll
  for (int nt = 0; nt < 4; ++nt) {
    const float ct = cv[nt * 16 + l15];
#pragma unroll
    for (int mt = 0; mt < 2; ++mt) {
      acc[mt][nt][0] *= ct; acc[mt][nt][1] *= ct;
      acc[mt][nt][2] *= ct; acc[mt][nt][3] *= ct;
    }
  }

  // ---- T = Q K^T for this t-half.  M=s (A-op = K rows, global),
  //      N=t (B-op = QBh).  Wave owns s-tile; loops 4 t-tiles. ----
  {
    const int mA = wave * 16;           // s-tile base (global s)
    f4v accA[4];
#pragma unroll
    for (int i = 0; i < 4; ++i) accA[i] = (f4v){0.f, 0.f, 0.f, 0.f};
#pragma unroll
    for (int kd = 0; kd < 8; ++kd) {
      const int d0 = kd * 32 + quad * 8;
      const float* krow = kbase + (size_t)(mA + l15) * D_ + d0;
      const s8v afr = pack8(*(const float4*)krow, *(const float4*)(krow + 4));
#pragma unroll
      for (int nt = 0; nt < 4; ++nt) {
        const s8v bf = *(const s8v*)&QB[(nt * 16 + l15) * 264 + d0];
        accA[nt] = __builtin_amdgcn_mfma_f32_16x16x32_bf16(afr, bf, accA[nt],
                                                           0, 0, 0);
      }
    }
    // rows = s (quad*4+r), cols = t_loc (l15): mask+decay, pack s-pairs
#pragma unroll
    for (int nt = 0; nt < 4; ++nt) {
      const int t_loc = nt * 16 + l15;
      const int t = th * 64 + t_loc;
      const float lt = ls[t];
      const int s0 = mA + quad * 4;
      float v[4];
#pragma unroll
      for (int r = 0; r < 4; ++r) {
        const int s = s0 + r;
        v[r] = (s <= t) ? accA[nt][r] * exp2f(lt - ls[s]) : 0.f;
      }
      uint2 w;
      w.x = pk2(v[0], v[1]);
      w.y = pk2(v[2], v[3]);
      *(uint2*)&Tm[t_loc * 136 + s0] = w;
    }
  }

  // ---- Tm @ V over 4 s-quarters; V^T staged per quarter ----
#pragma unroll
  for (int sq = 0; sq < 4; ++sq) {
    __syncthreads();   // Tm ready (sq=0) / previous quarter's reads done
    {
      const int jL = tid & 15;
      const int sp = (tid >> 4) & 15;           // s-pair within quarter
      const int hb = tid >> 8;                  // j upper half bit
      const int s0 = sp * 2;
      const int sg = sq * 32 + s0;
      const float* src0 = vbase + (size_t)sg * D_;
      const float* src1 = src0 + D_;
#pragma unroll
      for (int p = 0; p < 2; ++p) {
        const int j0 = hb * 128 + p * 64 + jL * 4;
        float a0[4], a1[4];
        *(float4*)a0 = *(const float4*)(src0 + j0);
        *(float4*)a1 = *(const float4*)(src1 + j0);
#pragma unroll
        for (int u = 0; u < 4; ++u)
          *(u32*)&VT[(j0 + u) * 34 + s0] = pk2(a0[u], a1[u]);
      }
    }
    __syncthreads();
    const int so = quad * 8;                    // within-quarter s offset
    s8v afv[2], bf[4];
#pragma unroll
    for (int mt = 0; mt < 2; ++mt)
      afv[mt] = *(const s8v*)&VT[(j0w + mt * 16 + l15) * 34 + so];
#pragma unroll
    for (int nt = 0; nt < 4; ++nt)
      bf[nt] = *(const s8v*)&Tm[(nt * 16 + l15) * 136 + sq * 32 + so];
#pragma unroll
    for (int mt = 0; mt < 2; ++mt)
#pragma unroll
      for (int nt = 0; nt < 4; ++nt)
        acc[mt][nt] = __builtin_amdgcn_mfma_f32_16x16x32_bf16(
            afv[mt], bf[nt], acc[mt][nt], 0, 0, 0);
  }

  // ---- epilogue: float4 stores (r runs along j) ----
  float* ob = outg + ((size_t)b * S_ + (size_t)c * L_ + th * 64) * D_;
#pragma unroll
  for (int mt = 0; mt < 2; ++mt)
#pragma unroll
    for (int nt = 0; nt < 4; ++nt) {
      const int t_loc = nt * 16 + l15;
      const int j0 = j0w + mt * 16 + quad * 4;
      float4 o;
      o.x = acc[mt][nt][0]; o.y = acc[mt][nt][1];
      o.z = acc[mt][nt][2]; o.w = acc[mt][nt][3];
      *(float4*)(ob + (size_t)t_loc * D_ + j0) = o;
    }
}

// ---------------------------------------------------------------------------
extern "C" void kernel_launch(void* const* d_in, const int* in_sizes, int n_in,
                              void* d_out, int out_size, void* d_ws,
                              size_t ws_size, hipStream_t stream) {
  const float* q = (const float*)d_in[0];
  const float* k = (const float*)d_in[1];
  const float* v = (const float*)d_in[2];
  const float* beta = (const float*)d_in[3];
  float* out = (float*)d_out;

  u16* A = (u16*)d_ws;                                   // 33.5 MB bf16 state
  float* P = (float*)((char*)d_ws + (size_t)BC_ * D_ * D_ * sizeof(u16));

  ks_summary7<<<dim3(BC_ * 2), dim3(512), 0, stream>>>(k, v, beta, A, P);
  ks_scan7<<<dim3(512), dim3(256), 0, stream>>>(A, P);
  ks_output7<<<dim3(BC_ * 2), dim3(512), 0, stream>>>(q, k, v, beta, A, out);
}

// Round 8
// 179.040 us; speedup vs baseline: 1.0724x; 1.0724x over previous
//
#include <hip/hip_runtime.h>
#include <hip/hip_bf16.h>
#include <math.h>

// Delta-rule linear attention, chunked + MFMA bf16, bf16 state buffer.
// B=8, S=4096, D=256, L=128 -> C=32 chunks/batch, 256 chunks total.
// 1024-thread blocks (16 waves), 1 block/CU: 2x TLP of R6 with NO traffic
// duplication (R7's split duplicated K/H/V reads - regressed).
// ws: A/H buffer [256][256][256] bf16 in TRANSPOSED [j][i] layout (33.5 MB),
//     then P [256] f32.

#define B_ 8
#define S_ 4096
#define D_ 256
#define L_ 128
#define C_ (S_ / L_)      // 32
#define BC_ (B_ * C_)     // 256

typedef __attribute__((ext_vector_type(8))) short s8v;   // 8 bf16 (4 VGPR)
typedef __attribute__((ext_vector_type(4))) float f4v;   // MFMA acc
typedef unsigned short u16;
typedef unsigned int u32;

__device__ __forceinline__ u32 pk2(float lo, float hi) {  // v_cvt_pk_bf16_f32
  union { __hip_bfloat162 h; u32 u; } cv;
  cv.h = __float22bfloat162_rn(make_float2(lo, hi));
  return cv.u;
}
__device__ __forceinline__ s8v pack8(const float4 a, const float4 b) {
  union { u32 u[4]; s8v v; } r;
  r.u[0] = pk2(a.x, a.y); r.u[1] = pk2(a.z, a.w);
  r.u[2] = pk2(b.x, b.y); r.u[3] = pk2(b.z, b.w);
  return r.v;
}

// 128-step prefix log2(beta) scan by wave 0 into ls[].
__device__ __forceinline__ void beta_scan128(const float* betap, float* ls,
                                             int tid) {
  if (tid < 64) {
    float x = log2f(fmaxf(betap[tid], 1e-30f));
#pragma unroll
    for (int off = 1; off < 64; off <<= 1) {
      float y = __shfl_up(x, off);
      if (tid >= off) x += y;
    }
    ls[tid] = x;
    const float tot0 = __shfl(x, 63);
    float z = log2f(fmaxf(betap[64 + tid], 1e-30f));
#pragma unroll
    for (int off = 1; off < 64; off <<= 1) {
      float y = __shfl_up(z, off);
      if (tid >= off) z += y;
    }
    ls[64 + tid] = z + tot0;
  }
}

// ---------------------------------------------------------------------------
// Kernel 1: A[bc][j][i] = sum_{s<128} w_s k_s[i] v_s[j]  (bf16, [j][i]).
// 1024 thr / 16 waves; wave owns a 16-i strip.  LDS ~102 KB, 1 block/CU.
// ---------------------------------------------------------------------------
__global__ __launch_bounds__(1024, 1) void ks_summary8(
    const float* __restrict__ kg, const float* __restrict__ vg,
    const float* __restrict__ beta, u16* __restrict__ A,
    float* __restrict__ P)
{
  __shared__ float ls[L_];
  __shared__ __align__(16) u16 U[2][256 * 66];   // K^T halves, then V^T halves
  __shared__ __align__(16) u16 BN[64 * 264];     // bounce [64 j][264 i-pad]

  const int bc = blockIdx.x;
  const int b = bc / C_, c = bc % C_;
  const int tid = threadIdx.x;
  const float* betap = beta + (size_t)b * S_ + (size_t)c * L_;
  const float* kbase = kg + ((size_t)b * S_ + (size_t)c * L_) * D_;
  const float* vbase = vg + ((size_t)b * S_ + (size_t)c * L_) * D_;

  beta_scan128(betap, ls, tid);
  __syncthreads();
  const float ltot = ls[L_ - 1];
  if (tid == 0) P[bc] = exp2f(ltot);

  const int hh = tid >> 9;            // s-half this thread stages
  const int t2 = tid & 511;
  const int iLs = t2 & 15;
  const int sps = t2 >> 4;            // 0..31 s-pair
  const int s0s = sps * 2;
  const int sg = hh * 64 + s0s;

  // ---- stage w-scaled K^T (both halves at once) ----
  {
    const float* src0 = kbase + (size_t)sg * D_;
    const float* src1 = src0 + D_;
    const float w0 = exp2f(ltot - ls[sg]);
    const float w1 = exp2f(ltot - ls[sg + 1]);
    u16* dst = U[hh];
#pragma unroll
    for (int p = 0; p < 4; ++p) {
      const int i0 = p * 64 + iLs * 4;
      float a0[4], a1[4];
      *(float4*)a0 = *(const float4*)(src0 + i0);
      *(float4*)a1 = *(const float4*)(src1 + i0);
#pragma unroll
      for (int u = 0; u < 4; ++u)
        *(u32*)&dst[(i0 + u) * 66 + s0s] = pk2(a0[u] * w0, a1[u] * w1);
    }
  }
  __syncthreads();

  const int lane = tid & 63, wave = tid >> 6;
  const int quad = lane >> 4, l15 = lane & 15;
  const int i0w = wave * 16;          // 16-i strip for this wave

  // cache A-operand (K^T) fragments covering all 4 k-steps (s=128)
  s8v af[4];
#pragma unroll
  for (int ks = 0; ks < 4; ++ks)
    af[ks] = *(const s8v*)&U[ks >> 1][(i0w + l15) * 66 +
                                      (ks & 1) * 32 + quad * 8];
  __syncthreads();

  // ---- stage V^T over K^T's LDS ----
  {
    const float* src0 = vbase + (size_t)sg * D_;
    const float* src1 = src0 + D_;
    u16* dst = U[hh];
#pragma unroll
    for (int p = 0; p < 4; ++p) {
      const int i0 = p * 64 + iLs * 4;
      float a0[4], a1[4];
      *(float4*)a0 = *(const float4*)(src0 + i0);
      *(float4*)a1 = *(const float4*)(src1 + i0);
#pragma unroll
      for (int u = 0; u < 4; ++u)
        *(u32*)&dst[(i0 + u) * 66 + s0s] = pk2(a0[u], a1[u]);
    }
  }
  __syncthreads();

  u16* Ab = A + (size_t)bc * D_ * D_;

  for (int ng = 0; ng < 4; ++ng) {    // j-groups of 64
    f4v acc[4];
#pragma unroll
    for (int nt = 0; nt < 4; ++nt) acc[nt] = (f4v){0.f, 0.f, 0.f, 0.f};

#pragma unroll
    for (int ks = 0; ks < 4; ++ks) {
      const int so = (ks & 1) * 32 + quad * 8;
      s8v bv[4];
#pragma unroll
      for (int nt = 0; nt < 4; ++nt)
        bv[nt] = *(const s8v*)&U[ks >> 1][(ng * 64 + nt * 16 + l15) * 66 + so];
#pragma unroll
      for (int nt = 0; nt < 4; ++nt)
        acc[nt] = __builtin_amdgcn_mfma_f32_16x16x32_bf16(
            af[ks], bv[nt], acc[nt], 0, 0, 0);
    }
    // C-frags -> bounce (r runs along i: in-lane packing)
#pragma unroll
    for (int nt = 0; nt < 4; ++nt) {
      const int jl = nt * 16 + l15;
      uint2 w;
      w.x = pk2(acc[nt][0], acc[nt][1]);
      w.y = pk2(acc[nt][2], acc[nt][3]);
      *(uint2*)&BN[jl * 264 + i0w + quad * 4] = w;
    }
    __syncthreads();
    // coalesced copy-out: 64 rows x 512 B
    {
      const int jl = tid >> 4;
      const int il = (tid & 15) * 8;
#pragma unroll
      for (int p = 0; p < 2; ++p) {
        const int iu = il + p * 128;
        *(s8v*)&Ab[(size_t)(ng * 64 + jl) * D_ + iu] =
            *(const s8v*)&BN[jl * 264 + iu];
      }
    }
    __syncthreads();
  }
}

// ---------------------------------------------------------------------------
// Kernel 2: register-batched chunk scan (unchanged).
// ---------------------------------------------------------------------------
__global__ __launch_bounds__(256) void ks_scan8(
    u16* __restrict__ A, const float* __restrict__ P)
{
  const int g = blockIdx.x;                       // 512 blocks
  const int b = g >> 6;                           // 64 blocks / batch
  const int unit = ((g & 63) << 8) + threadIdx.x; // uint2 unit 0..16383
  u16* base = A + (size_t)b * ((size_t)C_ * D_ * D_) + (size_t)unit * 4;
  const float* Pb = P + b * C_;

  uint2 d[C_];
#pragma unroll
  for (int c = 0; c < C_; ++c)
    d[c] = *(const uint2*)(base + (size_t)c * (D_ * D_));

  float h0 = 0.f, h1 = 0.f, h2 = 0.f, h3 = 0.f;
#pragma unroll
  for (int c = 0; c < C_; ++c) {
    const float pc = Pb[c];
    const uint2 u = d[c];
    const float a0 = __uint_as_float(u.x << 16);
    const float a1 = __uint_as_float(u.x & 0xFFFF0000u);
    const float a2 = __uint_as_float(u.y << 16);
    const float a3 = __uint_as_float(u.y & 0xFFFF0000u);
    d[c].x = pk2(h0, h1);
    d[c].y = pk2(h2, h3);
    h0 = fmaf(pc, h0, a0); h1 = fmaf(pc, h1, a1);
    h2 = fmaf(pc, h2, a2); h3 = fmaf(pc, h3, a3);
  }
#pragma unroll
  for (int c = 0; c < C_; ++c)
    *(uint2*)(base + (size_t)c * (D_ * D_)) = d[c];
}

// ---------------------------------------------------------------------------
// Kernel 3: O = Tm @ V + diag(c) Q @ H.  1024 thr / 16 waves, 1 block/CU.
// Wave owns a 16-j strip (QH, TmV) and one (s-tile x 4 t-tiles) of phase A.
// ---------------------------------------------------------------------------
__global__ __launch_bounds__(1024, 1) void ks_output8(
    const float* __restrict__ qg, const float* __restrict__ kg,
    const float* __restrict__ vg, const float* __restrict__ beta,
    const u16* __restrict__ Hg, float* __restrict__ outg)
{
  __shared__ float ls[L_];
  __shared__ float cv[L_];
  __shared__ __align__(16) u16 QB[L_ * 264];     // [t][d] bf16   (67.6 KB)
  __shared__ __align__(16) u16 Tm[L_ * 136];     // [t][s] bf16   (34.8 KB)
  __shared__ __align__(16) u16 VT[256 * 66];     // [j][s-half]   (33.8 KB)

  const int bc = blockIdx.x;
  const int b = bc / C_, c = bc % C_;
  const int tid = threadIdx.x;
  const float* betap = beta + (size_t)b * S_ + (size_t)c * L_;
  const float* qbase = qg + ((size_t)b * S_ + (size_t)c * L_) * D_;
  const float* kbase = kg + ((size_t)b * S_ + (size_t)c * L_) * D_;
  const float* vbase = vg + ((size_t)b * S_ + (size_t)c * L_) * D_;
  const u16* Hb = Hg + (size_t)bc * D_ * D_;

  beta_scan128(betap, ls, tid);

  // ---- stage QB row-major bf16 ----
  {
    const int t = tid >> 3;
    const int d8 = (tid & 7) * 8;
    const float* src = qbase + (size_t)t * D_;
#pragma unroll
    for (int p = 0; p < 4; ++p) {
      const int d0 = d8 + p * 64;
      const s8v pk = pack8(*(const float4*)(src + d0),
                           *(const float4*)(src + d0 + 4));
      *(s8v*)&QB[t * 264 + d0] = pk;
    }
  }
  __syncthreads();
  if (tid < L_) cv[tid] = exp2f(ls[tid]);   // c_t

  const int lane = tid & 63, wave = tid >> 6;
  const int quad = lane >> 4, l15 = lane & 15;
  const int j0w = wave * 16;

  // ---- phase A: T = Q K^T.  wave: s-tile (w&7), t-tiles (w>>3)*4.. ----
  {
    const int mA = (wave & 7) * 16;     // s-tile base
    const int tg = (wave >> 3) * 64;    // t-group base
    f4v accA[4];
#pragma unroll
    for (int i = 0; i < 4; ++i) accA[i] = (f4v){0.f, 0.f, 0.f, 0.f};
#pragma unroll
    for (int kd = 0; kd < 8; ++kd) {
      const int d0 = kd * 32 + quad * 8;
      const float* krow = kbase + (size_t)(mA + l15) * D_ + d0;
      const s8v afr = pack8(*(const float4*)krow, *(const float4*)(krow + 4));
#pragma unroll
      for (int nt = 0; nt < 4; ++nt) {
        const s8v bf = *(const s8v*)&QB[(tg + nt * 16 + l15) * 264 + d0];
        accA[nt] = __builtin_amdgcn_mfma_f32_16x16x32_bf16(afr, bf, accA[nt],
                                                           0, 0, 0);
      }
    }
    // rows = s (quad*4+r), cols = t (l15): mask+decay, pack s-pairs
#pragma unroll
    for (int nt = 0; nt < 4; ++nt) {
      const int t = tg + nt * 16 + l15;
      const float lt = ls[t];
      const int s0 = mA + quad * 4;
      float v[4];
#pragma unroll
      for (int r = 0; r < 4; ++r) {
        const int s = s0 + r;
        v[r] = (s <= t) ? accA[nt][r] * exp2f(lt - ls[s]) : 0.f;
      }
      uint2 w;
      w.x = pk2(v[0], v[1]);
      w.y = pk2(v[2], v[3]);
      *(uint2*)&Tm[t * 136 + s0] = w;
    }
  }

  // ---- stage VT half 0 (independent of Tm; before the barrier) ----
  {
    const int jL = tid & 15;
    const int sp = (tid >> 4) & 31;
    const int hb = tid >> 9;
    const int s0 = sp * 2;
    const float* src0 = vbase + (size_t)s0 * D_ + hb * 128;
    const float* src1 = src0 + D_;
#pragma unroll
    for (int p = 0; p < 2; ++p) {
      const int j0 = hb * 128 + p * 64 + jL * 4;
      float a0[4], a1[4];
      *(float4*)a0 = *(const float4*)(src0 + p * 64 + jL * 4);
      *(float4*)a1 = *(const float4*)(src1 + p * 64 + jL * 4);
#pragma unroll
      for (int u = 0; u < 4; ++u)
        *(u32*)&VT[(j0 + u) * 66 + s0] = pk2(a0[u], a1[u]);
    }
  }

  // preload first H k-step
  s8v hc = *(const s8v*)(Hb + (size_t)(j0w + l15) * D_ + quad * 8);

  __syncthreads();   // Tm + VT(h0) visible

  // ---- Q @ H into acc, H loads pipelined one step ahead ----
  f4v acc[8];
#pragma unroll
  for (int nt = 0; nt < 8; ++nt) acc[nt] = (f4v){0.f, 0.f, 0.f, 0.f};

#pragma unroll
  for (int ks = 0; ks < 8; ++ks) {
    const int io = ks * 32 + quad * 8;
    s8v hn = hc;
    if (ks < 7)
      hn = *(const s8v*)(Hb + (size_t)(j0w + l15) * D_ + io + 32);
    s8v bf[8];
#pragma unroll
    for (int nt = 0; nt < 8; ++nt)
      bf[nt] = *(const s8v*)&QB[(nt * 16 + l15) * 264 + io];
#pragma unroll
    for (int nt = 0; nt < 8; ++nt)
      acc[nt] = __builtin_amdgcn_mfma_f32_16x16x32_bf16(hc, bf[nt], acc[nt],
                                                        0, 0, 0);
    hc = hn;
  }
  // scale by c_t  (t = nt*16 + l15 constant per lane per nt)
#pragma unroll
  for (int nt = 0; nt < 8; ++nt) {
    const float ct = cv[nt * 16 + l15];
    acc[nt][0] *= ct; acc[nt][1] *= ct;
    acc[nt][2] *= ct; acc[nt][3] *= ct;
  }

  // ---- Tm @ V half 0 (VT already staged) ----
#pragma unroll
  for (int ks = 0; ks < 2; ++ks) {
    const int so = ks * 32 + quad * 8;
    const s8v afv = *(const s8v*)&VT[(j0w + l15) * 66 + so];
    s8v bf[8];
#pragma unroll
    for (int nt = 0; nt < 8; ++nt)
      bf[nt] = *(const s8v*)&Tm[(nt * 16 + l15) * 136 + so];
#pragma unroll
    for (int nt = 0; nt < 8; ++nt)
      acc[nt] = __builtin_amdgcn_mfma_f32_16x16x32_bf16(afv, bf[nt], acc[nt],
                                                        0, 0, 0);
  }

  // ---- Tm @ V half 1: restage VT, then accumulate ----
  __syncthreads();
  {
    const int jL = tid & 15;
    const int sp = (tid >> 4) & 31;
    const int hb = tid >> 9;
    const int s0 = sp * 2;
    const float* src0 = vbase + (size_t)(64 + s0) * D_ + hb * 128;
    const float* src1 = src0 + D_;
#pragma unroll
    for (int p = 0; p < 2; ++p) {
      const int j0 = hb * 128 + p * 64 + jL * 4;
      float a0[4], a1[4];
      *(float4*)a0 = *(const float4*)(src0 + p * 64 + jL * 4);
      *(float4*)a1 = *(const float4*)(src1 + p * 64 + jL * 4);
#pragma unroll
      for (int u = 0; u < 4; ++u)
        *(u32*)&VT[(j0 + u) * 66 + s0] = pk2(a0[u], a1[u]);
    }
  }
  __syncthreads();
#pragma unroll
  for (int ks = 0; ks < 2; ++ks) {
    const int so = ks * 32 + quad * 8;
    const s8v afv = *(const s8v*)&VT[(j0w + l15) * 66 + so];
    s8v bf[8];
#pragma unroll
    for (int nt = 0; nt < 8; ++nt)
      bf[nt] = *(const s8v*)&Tm[(nt * 16 + l15) * 136 + 64 + so];
#pragma unroll
    for (int nt = 0; nt < 8; ++nt)
      acc[nt] = __builtin_amdgcn_mfma_f32_16x16x32_bf16(afv, bf[nt], acc[nt],
                                                        0, 0, 0);
  }

  // ---- epilogue: float4 stores (r runs along j) ----
  float* ob = outg + ((size_t)b * S_ + (size_t)c * L_) * D_;
#pragma unroll
  for (int nt = 0; nt < 8; ++nt) {
    const int t = nt * 16 + l15;
    const int j0 = j0w + quad * 4;
    float4 o;
    o.x = acc[nt][0]; o.y = acc[nt][1];
    o.z = acc[nt][2]; o.w = acc[nt][3];
    *(float4*)(ob + (size_t)t * D_ + j0) = o;
  }
}

// ---------------------------------------------------------------------------
extern "C" void kernel_launch(void* const* d_in, const int* in_sizes, int n_in,
                              void* d_out, int out_size, void* d_ws,
                              size_t ws_size, hipStream_t stream) {
  const float* q = (const float*)d_in[0];
  const float* k = (const float*)d_in[1];
  const float* v = (const float*)d_in[2];
  const float* beta = (const float*)d_in[3];
  float* out = (float*)d_out;

  u16* A = (u16*)d_ws;                                   // 33.5 MB bf16 state
  float* P = (float*)((char*)d_ws + (size_t)BC_ * D_ * D_ * sizeof(u16));

  ks_summary8<<<dim3(BC_), dim3(1024), 0, stream>>>(k, v, beta, A, P);
  ks_scan8<<<dim3(512), dim3(256), 0, stream>>>(A, P);
  ks_output8<<<dim3(BC_), dim3(1024), 0, stream>>>(q, k, v, beta, A, out);
}